// Round 7
// baseline (55.707 us; speedup 1.0000x reference)
//
#include <hip/hip_runtime.h>

#define B_N   2048
#define LQ    10
#define LH    150

// One wave (64 lanes) per batch element. lane = rg*16 + c:
//   rg = lane>>4 owns pixel rows 4*rg..4*rg+3, column c = lane&15.
//
// VI loop is REGISTER-ONLY: v[4] per lane, halo via 14 __shfl (ds_bpermute)
// per step, boundary zeros via masks. No LDS, no barriers in the loop
// (rounds 5/6 showed the per-step LDS round-trip + barrier was the wall:
// VALUBusy stuck at 41-58% while dur didn't move).
//
// LDS arena (prologue only):
//   xs   [0,648)   : padded X, ch*324 + y*18 + x   (stride 18: 2-way banks)
//   rp   [648,972) : padded r
//   effs [972,1000): [0..17] eff_w, [18] eff_b, [19..27] fw
//   scr  [1000,1064): reduction scratch
// No runtime indexing into any register array (round-4 lesson).
__global__ __launch_bounds__(64, 2) void vin_kernel(
    const float* __restrict__ X,   const float* __restrict__ S1,
    const float* __restrict__ S2,  const float* __restrict__ h_w,
    const float* __restrict__ h_b, const float* __restrict__ r_w,
    const float* __restrict__ qw,  const float* __restrict__ w,
    const float* __restrict__ fcw, float* __restrict__ out)
{
    __shared__ float smem[1064];
    float* xs   = smem;
    float* rp   = smem + 648;
    float* effs = smem + 972;
    float* scr  = smem + 1000;

    const int b    = blockIdx.x;
    const int lane = threadIdx.x;
    const int rg   = lane >> 4;
    const int c    = lane & 15;

    // ---- issue X loads first (HBM latency overlaps the weight reduction) ----
    const float* Xb = X + (size_t)b * 512;
    float xreg[8];
    #pragma unroll
    for (int k = 0; k < 8; ++k) xreg[k] = Xb[lane + (k << 6)];

    // ---- zero arena (conv borders must be 0) ----
    #pragma unroll
    for (int k = 0; k < 17; ++k) {
        int idx = lane + (k << 6);
        if (idx < 1064) smem[idx] = 0.f;
    }

    // ---- collapsed-weight partials (registers only before sync) ----
    // lanes 0..53: eff_w[t] partial, t=lane/3, chunk=(lane%3)*50
    // lanes 54..56: eff_b partial
    float part = 0.f;
    if (lane < 54) {
        const int t  = lane / 3;
        const int h0 = (lane - t * 3) * 50;
        for (int h = h0; h < h0 + 50; ++h) part += r_w[h] * h_w[h * 18 + t];
    } else if (lane < 57) {
        const int h0 = (lane - 54) * 50;
        for (int h = h0; h < h0 + 50; ++h) part += r_w[h] * h_b[h];
    }
    __syncthreads();                      // zero-fill visible

    scr[lane] = part;
    // stage X into padded LDS
    #pragma unroll
    for (int k = 0; k < 8; ++k) {
        int e = lane + (k << 6);
        int ch = e >> 8, rem = e & 255;
        xs[ch * 324 + ((rem >> 4) + 1) * 18 + (rem & 15) + 1] = xreg[k];
    }
    // fw[t] = sum_a fc_w[a]*w[a][t]  (lanes 19..27 -> effs[19..27])
    if (lane >= 19 && lane < 28) {
        const int t = lane - 19;
        float acc = 0.f;
        #pragma unroll
        for (int a = 0; a < LQ; ++a) acc += fcw[a] * w[a * 9 + t];
        effs[lane] = acc;
    }
    __syncthreads();

    if (lane < 18)       effs[lane] = scr[lane * 3] + scr[lane * 3 + 1] + scr[lane * 3 + 2];
    else if (lane == 18) effs[18]   = scr[54] + scr[55] + scr[56];
    __syncthreads();

    // ---- r = conv3x3(X, eff_w) + eff_b for this lane's 4 rows ----
    float ew[19];
    #pragma unroll
    for (int t = 0; t < 19; ++t) ew[t] = effs[t];

    float xt[2][6][3];
    #pragma unroll
    for (int ch = 0; ch < 2; ++ch)
        #pragma unroll
        for (int dy = 0; dy < 6; ++dy)
            #pragma unroll
            for (int dx = 0; dx < 3; ++dx)
                xt[ch][dy][dx] = xs[ch * 324 + ((rg << 2) + dy) * 18 + c + dx];

    #pragma unroll
    for (int k = 0; k < 4; ++k) {
        float acc = ew[18];
        #pragma unroll
        for (int ch = 0; ch < 2; ++ch)
            #pragma unroll
            for (int ky = 0; ky < 3; ++ky)
                #pragma unroll
                for (int kx = 0; kx < 3; ++kx)
                    acc += xt[ch][k + ky][kx] * ew[ch * 9 + ky * 3 + kx];
        rp[((rg << 2) + k + 1) * 18 + c + 1] = acc;
    }
    __syncthreads();

    // ---- qr[k][a] = conv3x3(r, q_w)[a] (iteration-invariant half) ----
    float rt[6][3];
    #pragma unroll
    for (int dy = 0; dy < 6; ++dy)
        #pragma unroll
        for (int dx = 0; dx < 3; ++dx)
            rt[dy][dx] = rp[((rg << 2) + dy) * 18 + c + dx];

    float qr[4][LQ];
    #pragma unroll
    for (int k = 0; k < 4; ++k)
        #pragma unroll
        for (int a = 0; a < LQ; ++a) {
            float acc = 0.f;
            #pragma unroll
            for (int ky = 0; ky < 3; ++ky)
                #pragma unroll
                for (int kx = 0; kx < 3; ++kx)
                    acc += rt[k + ky][kx] * qw[a * 9 + ky * 3 + kx];
            qr[k][a] = acc;
        }

    // ---- VI weights + fc via uniform pointers (compiler -> scalar regs) ----
    float wr[LQ * 9];
    #pragma unroll
    for (int t = 0; t < LQ * 9; ++t) wr[t] = w[t];
    float fc[LQ];
    #pragma unroll
    for (int a = 0; a < LQ; ++a) fc[a] = fcw[a];

    // ---- v0 = max_a qr, in registers ----
    float vv[4];
    #pragma unroll
    for (int k = 0; k < 4; ++k) {
        float m = qr[k][0];
        #pragma unroll
        for (int a = 1; a < LQ; ++a) m = fmaxf(m, qr[k][a]);
        vv[k] = m;
    }

    const bool top0 = (rg == 0), bot0 = (rg == 3);
    const bool lf0  = (c == 0),  rt0  = (c == 15);

    // Column stack Sk[6] = rows 4rg-1 .. 4rg+4 of own column; Lk/Rk = cols c-1/c+1.
    // Wrap-around shuffle garbage is masked to the conv zero-padding.
    float Sk[6], Lk[6], Rk[6];
#define HALO()                                                     \
    {                                                              \
        Sk[1] = vv[0]; Sk[2] = vv[1]; Sk[3] = vv[2]; Sk[4] = vv[3];\
        float t_ = __shfl(vv[3], lane - 16, 64);                   \
        float b_ = __shfl(vv[0], lane + 16, 64);                   \
        Sk[0] = top0 ? 0.f : t_;                                   \
        Sk[5] = bot0 ? 0.f : b_;                                   \
        _Pragma("unroll")                                          \
        for (int j = 0; j < 6; ++j) {                              \
            float l_ = __shfl(Sk[j], lane - 1, 64);                \
            float r_ = __shfl(Sk[j], lane + 1, 64);                \
            Lk[j] = lf0 ? 0.f : l_;                                \
            Rk[j] = rt0 ? 0.f : r_;                                \
        }                                                          \
    }

    // ---- 19 VI sweeps: barrier-free, LDS-free ----
    #pragma unroll 1
    for (int it = 0; it < 19; ++it) {
        HALO();
        float nv0, nv1, nv2, nv3;
        #pragma unroll
        for (int a = 0; a < LQ; ++a) {
            float a0 = qr[0][a], a1 = qr[1][a], a2 = qr[2][a], a3 = qr[3][a];
            #pragma unroll
            for (int dy = 0; dy < 3; ++dy) {
                const float w0 = wr[a * 9 + dy * 3 + 0];
                const float w1 = wr[a * 9 + dy * 3 + 1];
                const float w2 = wr[a * 9 + dy * 3 + 2];
                a0 += Lk[0 + dy] * w0; a0 += Sk[0 + dy] * w1; a0 += Rk[0 + dy] * w2;
                a1 += Lk[1 + dy] * w0; a1 += Sk[1 + dy] * w1; a1 += Rk[1 + dy] * w2;
                a2 += Lk[2 + dy] * w0; a2 += Sk[2 + dy] * w1; a2 += Rk[2 + dy] * w2;
                a3 += Lk[3 + dy] * w0; a3 += Sk[3 + dy] * w1; a3 += Rk[3 + dy] * w2;
            }
            if (a == 0) { nv0 = a0; nv1 = a1; nv2 = a2; nv3 = a3; }
            else {
                nv0 = fmaxf(nv0, a0); nv1 = fmaxf(nv1, a1);
                nv2 = fmaxf(nv2, a2); nv3 = fmaxf(nv3, a3);
            }
        }
        vv[0] = nv0; vv[1] = nv1; vv[2] = nv2; vv[3] = nv3;
    }

    // ---- one more halo for the final conv's v-taps ----
    HALO();

    const float s1f = S1[b], s2f = S2[b];
    int s1 = (int)floorf((s1f + 50.0f) / 6.25f);
    int s2 = (int)floorf((s2f + 50.0f) / 6.25f);
    s1 = min(max(s1, 0), 15);
    s2 = min(max(s2, 0), 15);

    if (rg == (s1 >> 2) && c == s2) {
        float fw[9];
        #pragma unroll
        for (int t = 0; t < 9; ++t) fw[t] = effs[19 + t];

        // static-index logits for all 4 candidate rows; scalar ternary select
        float g0 = 0.f, g1 = 0.f, g2 = 0.f, g3 = 0.f;
        #pragma unroll
        for (int a = 0; a < LQ; ++a) {
            g0 += fc[a] * qr[0][a]; g1 += fc[a] * qr[1][a];
            g2 += fc[a] * qr[2][a]; g3 += fc[a] * qr[3][a];
        }
        #pragma unroll
        for (int dy = 0; dy < 3; ++dy) {
            const float f0 = fw[dy * 3 + 0], f1 = fw[dy * 3 + 1], f2 = fw[dy * 3 + 2];
            g0 += Lk[0 + dy] * f0; g0 += Sk[0 + dy] * f1; g0 += Rk[0 + dy] * f2;
            g1 += Lk[1 + dy] * f0; g1 += Sk[1 + dy] * f1; g1 += Rk[1 + dy] * f2;
            g2 += Lk[2 + dy] * f0; g2 += Sk[2 + dy] * f1; g2 += Rk[2 + dy] * f2;
            g3 += Lk[3 + dy] * f0; g3 += Sk[3 + dy] * f1; g3 += Rk[3 + dy] * f2;
        }
        const int kk = s1 & 3;
        float logit = (kk == 0) ? g0 : (kk == 1) ? g1 : (kk == 2) ? g2 : g3;
        out[b]       = logit;   // logits
        out[B_N + b] = 1.0f;    // softmax over length-1 axis == 1
    }
#undef HALO
}

extern "C" void kernel_launch(void* const* d_in, const int* in_sizes, int n_in,
                              void* d_out, int out_size, void* d_ws, size_t ws_size,
                              hipStream_t stream) {
    const float* X    = (const float*)d_in[0];
    const float* S1   = (const float*)d_in[1];
    const float* S2   = (const float*)d_in[2];
    const float* h_w  = (const float*)d_in[3];
    const float* h_b  = (const float*)d_in[4];
    const float* r_w  = (const float*)d_in[5];
    const float* q_w  = (const float*)d_in[6];
    const float* w    = (const float*)d_in[7];
    const float* fc_w = (const float*)d_in[8];
    float*       out  = (float*)d_out;

    vin_kernel<<<B_N, 64, 0, stream>>>(X, S1, S2, h_w, h_b, r_w, q_w, w, fc_w, out);
}

// Round 8
// 44.997 us; speedup vs baseline: 1.2380x; 1.2380x over previous
//
#include <hip/hip_runtime.h>

#define B_N   2048
#define LQ    10
#define LH    150

// LDS arena (floats), row stride 20 -> max 2-way bank aliasing (free, m136):
//   XS  [0,720)    : padded X, ch*360 + (row+1)*20 + (col+1)
//   RP  [720,1080) : padded r
//   VP  [1080,1800): double-buffered padded v (VP+0 / VP+360)
//   EF  [1800,1828): [0..17] eff_w, [18] eff_b, [19..27] fw
//   SCR [1828,1956): reduction scratch (one slot per thread)
#define XS    0
#define RP    720
#define VP    1080
#define EF    1800
#define SCR   1828
#define SMEMN 1956

// 128 threads (2 waves) per batch element: tid = rg*16 + c, rg=0..7 owns
// rows 2rg,2rg+1, col c. 2048 blocks * 2 waves = 4 waves/SIMD (2x R5's
// latency hiding). Lean per-step structure (R6's mistake avoided): VI
// weights are wave-uniform w[] loads -> SGPRs (R5 evidence: SGPR=112),
// v-taps are 12 constant-offset ds_reads from one base (merge to read2),
// one ds_write2, one barrier. No runtime indexing into register arrays.
__global__ __launch_bounds__(128, 4) void vin_kernel(
    const float* __restrict__ X,   const float* __restrict__ S1,
    const float* __restrict__ S2,  const float* __restrict__ h_w,
    const float* __restrict__ h_b, const float* __restrict__ r_w,
    const float* __restrict__ qw,  const float* __restrict__ w,
    const float* __restrict__ fcw, float* __restrict__ out)
{
    __shared__ float smem[SMEMN];

    const int b   = blockIdx.x;
    const int tid = threadIdx.x;
    const int rg  = tid >> 4;     // 0..7
    const int c   = tid & 15;

    // ---- issue X loads first (HBM latency overlaps weight reduction) ----
    const float* Xb = X + (size_t)b * 512;
    float xreg[4];
    #pragma unroll
    for (int k = 0; k < 4; ++k) xreg[k] = Xb[tid + (k << 7)];

    // ---- zero arena (conv borders must be 0) ----
    #pragma unroll
    for (int k = 0; k < 16; ++k) {
        int idx = tid + (k << 7);
        if (idx < SMEMN) smem[idx] = 0.f;
    }

    // ---- collapsed-weight partials: 7 lanes per tap, 22 h's per lane ----
    float part = 0.f;
    if (tid < 126) {
        const int t  = tid / 7;
        const int j  = tid - t * 7;
        const int h0 = j * 22;
        const int h1 = (h0 + 22 < LH) ? h0 + 22 : LH;
        for (int h = h0; h < h1; ++h) part += r_w[h] * h_w[h * 18 + t];
    } else {
        const int h0 = (tid - 126) * 75;
        for (int h = h0; h < h0 + 75; ++h) part += r_w[h] * h_b[h];
    }
    __syncthreads();                       // zero-fill visible

    smem[SCR + tid] = part;
    // stage X into padded LDS
    #pragma unroll
    for (int k = 0; k < 4; ++k) {
        int e = tid + (k << 7);
        int ch = e >> 8, rem = e & 255;
        smem[XS + ch * 360 + ((rem >> 4) + 1) * 20 + (rem & 15) + 1] = xreg[k];
    }
    __syncthreads();

    if (tid < 18) {
        float s = 0.f;
        #pragma unroll
        for (int j = 0; j < 7; ++j) s += smem[SCR + tid * 7 + j];
        smem[EF + tid] = s;
    } else if (tid == 18) {
        smem[EF + 18] = smem[SCR + 126] + smem[SCR + 127];
    } else if (tid >= 19 && tid < 28) {
        const int t = tid - 19;
        float acc = 0.f;
        #pragma unroll
        for (int a = 0; a < LQ; ++a) acc += fcw[a] * w[a * 9 + t];
        smem[EF + tid] = acc;              // fw
    }
    __syncthreads();

    // ---- r = conv3x3(X, eff_w) + eff_b for this lane's 2 rows ----
    float ew[19];
    #pragma unroll
    for (int t = 0; t < 19; ++t) ew[t] = smem[EF + t];

    float xt[2][4][3];
    #pragma unroll
    for (int ch = 0; ch < 2; ++ch)
        #pragma unroll
        for (int dy = 0; dy < 4; ++dy)
            #pragma unroll
            for (int dx = 0; dx < 3; ++dx)
                xt[ch][dy][dx] = smem[XS + ch * 360 + ((rg << 1) + dy) * 20 + c + dx];

    #pragma unroll
    for (int k = 0; k < 2; ++k) {
        float acc = ew[18];
        #pragma unroll
        for (int ch = 0; ch < 2; ++ch)
            #pragma unroll
            for (int ky = 0; ky < 3; ++ky)
                #pragma unroll
                for (int kx = 0; kx < 3; ++kx)
                    acc += xt[ch][k + ky][kx] * ew[ch * 9 + ky * 3 + kx];
        smem[RP + ((rg << 1) + k + 1) * 20 + c + 1] = acc;
    }
    __syncthreads();

    // ---- qr[k][a] = conv3x3(r, q_w)[a] (iteration-invariant half) ----
    float rt[4][3];
    #pragma unroll
    for (int dy = 0; dy < 4; ++dy)
        #pragma unroll
        for (int dx = 0; dx < 3; ++dx)
            rt[dy][dx] = smem[RP + ((rg << 1) + dy) * 20 + c + dx];

    float qr[2][LQ];
    #pragma unroll
    for (int a = 0; a < LQ; ++a)
        #pragma unroll
        for (int k = 0; k < 2; ++k) {
            float acc = 0.f;
            #pragma unroll
            for (int ky = 0; ky < 3; ++ky)
                #pragma unroll
                for (int kx = 0; kx < 3; ++kx)
                    acc += rt[k + ky][kx] * qw[a * 9 + ky * 3 + kx];
            qr[k][a] = acc;
        }

    // ---- VI weights via wave-uniform loads -> SGPRs ----
    float wr[LQ * 9];
    #pragma unroll
    for (int t = 0; t < LQ * 9; ++t) wr[t] = w[t];
    float fc[LQ];
    #pragma unroll
    for (int a = 0; a < LQ; ++a) fc[a] = fcw[a];

    // ---- v0 = max_a qr ----
    #pragma unroll
    for (int k = 0; k < 2; ++k) {
        float m = qr[k][0];
        #pragma unroll
        for (int a = 1; a < LQ; ++a) m = fmaxf(m, qr[k][a]);
        smem[VP + ((rg << 1) + k + 1) * 20 + c + 1] = m;
    }
    __syncthreads();

    // ---- 19 VI sweeps: 12 const-offset reads + 1 write2 + 1 barrier ----
#define VSTEP(SRC, DST)                                                        \
    {                                                                          \
        float vt[4][3];                                                        \
        _Pragma("unroll")                                                      \
        for (int dy = 0; dy < 4; ++dy)                                         \
            _Pragma("unroll")                                                  \
            for (int dx = 0; dx < 3; ++dx)                                     \
                vt[dy][dx] = smem[VP + (SRC) + ((rg << 1) + dy) * 20 + c + dx];\
        float m0, m1;                                                          \
        _Pragma("unroll")                                                      \
        for (int a = 0; a < LQ; ++a) {                                         \
            float a0 = qr[0][a], a1 = qr[1][a];                                \
            _Pragma("unroll")                                                  \
            for (int dy = 0; dy < 3; ++dy) {                                   \
                const float w0 = wr[a * 9 + dy * 3 + 0];                       \
                const float w1 = wr[a * 9 + dy * 3 + 1];                       \
                const float w2 = wr[a * 9 + dy * 3 + 2];                       \
                a0 += vt[0 + dy][0] * w0; a0 += vt[0 + dy][1] * w1;            \
                a0 += vt[0 + dy][2] * w2;                                      \
                a1 += vt[1 + dy][0] * w0; a1 += vt[1 + dy][1] * w1;            \
                a1 += vt[1 + dy][2] * w2;                                      \
            }                                                                  \
            if (a == 0) { m0 = a0; m1 = a1; }                                  \
            else        { m0 = fmaxf(m0, a0); m1 = fmaxf(m1, a1); }            \
        }                                                                      \
        smem[VP + (DST) + ((rg << 1) + 1) * 20 + c + 1] = m0;                  \
        smem[VP + (DST) + ((rg << 1) + 2) * 20 + c + 1] = m1;                  \
        __syncthreads();                                                       \
    }

    #pragma unroll 1
    for (int it = 0; it < 9; ++it) {
        VSTEP(0, 360)
        VSTEP(360, 0)
    }
    VSTEP(0, 360)   // step 19; final v in VP+360

    // ---- final conv + gather + fc at (s1, s2) only ----
    const float s1f = S1[b], s2f = S2[b];
    int s1 = (int)floorf((s1f + 50.0f) / 6.25f);
    int s2 = (int)floorf((s2f + 50.0f) / 6.25f);
    s1 = min(max(s1, 0), 15);
    s2 = min(max(s2, 0), 15);

    if (rg == (s1 >> 1) && c == s2) {
        float d0 = 0.f, d1 = 0.f;
        #pragma unroll
        for (int a = 0; a < LQ; ++a) {
            d0 += fc[a] * qr[0][a];
            d1 += fc[a] * qr[1][a];
        }
        float logit = ((s1 & 1) == 0) ? d0 : d1;
        #pragma unroll
        for (int ky = 0; ky < 3; ++ky)
            #pragma unroll
            for (int kx = 0; kx < 3; ++kx)
                logit += smem[VP + 360 + (s1 + ky) * 20 + s2 + kx]
                       * smem[EF + 19 + ky * 3 + kx];
        out[b]       = logit;   // logits
        out[B_N + b] = 1.0f;    // softmax over length-1 axis == 1
    }
#undef VSTEP
}

extern "C" void kernel_launch(void* const* d_in, const int* in_sizes, int n_in,
                              void* d_out, int out_size, void* d_ws, size_t ws_size,
                              hipStream_t stream) {
    const float* X    = (const float*)d_in[0];
    const float* S1   = (const float*)d_in[1];
    const float* S2   = (const float*)d_in[2];
    const float* h_w  = (const float*)d_in[3];
    const float* h_b  = (const float*)d_in[4];
    const float* r_w  = (const float*)d_in[5];
    const float* q_w  = (const float*)d_in[6];
    const float* w    = (const float*)d_in[7];
    const float* fc_w = (const float*)d_in[8];
    float*       out  = (float*)d_out;

    vin_kernel<<<B_N, 128, 0, stream>>>(X, S1, S2, h_w, h_b, r_w, q_w, w, fc_w, out);
}